// Round 6
// baseline (98.871 us; speedup 1.0000x reference)
//
#include <hip/hip_runtime.h>
#include <math.h>

#define Bq 512
#define Nq 128
#define Mq 256
#define Eq 64
#define NB 16              // row bands
#define LOG2E 1.4426950408889634f

// Workspace layout (float offsets). ~8.7 MB used.
#define WS_ZC 0                         // [512][128]
#define WS_A0 65536                     // [16][512][128]
#define WS_A1 1114112                   // [16][512][128]
#define WS_MZ 2162688                   // [16][512][2]

// Sum within each 16-lane group (4 DPP steps, never leaves the row-of-16).
#define DPPADD(X, CTRL) \
    (X) += __int_as_float(__builtin_amdgcn_update_dpp(0, __float_as_int(X), (CTRL), 0xf, 0xf, true));
__device__ __forceinline__ float red16(float x) {
    DPPADD(x, 0x0B1)  // quad_perm [1,0,3,2]  (xor1)
    DPPADD(x, 0x04E)  // quad_perm [2,3,0,1]  (xor2)
    DPPADD(x, 0x141)  // row_half_mirror      (xor4-equiv)
    DPPADD(x, 0x140)  // row_mirror           (xor8-equiv)
    return x;
}
#define DPPMAX(X, CTRL) \
    (X) = fmaxf((X), __int_as_float(__builtin_amdgcn_update_dpp(0, __float_as_int(X), (CTRL), 0xf, 0xf, true)));
__device__ __forceinline__ float red16max(float x) {
    DPPMAX(x, 0x0B1)
    DPPMAX(x, 0x04E)
    DPPMAX(x, 0x141)
    DPPMAX(x, 0x140)
    return x;
}

// ---- kernel0: zc[col][o] = D[o,:]·z[:,col] + sigma[o]*noise[o,col] ----
extern "C" __global__ void __launch_bounds__(512)
zc_kernel(const float* __restrict__ z, const float* __restrict__ noise,
          const float* __restrict__ D, const float* __restrict__ sigma,
          float* __restrict__ ws)
{
    const int b4 = blockIdx.x * 4;
    const int t  = threadIdx.x;
    __shared__ float zs[4][256];
    for (int i = t; i < 1024; i += 512)
        zs[i >> 8][i & 255] = z[(i & 255) * Bq + b4 + (i >> 8)];
    __syncthreads();
    const int c = t >> 7, o = t & 127;
    const float4* Dr = (const float4*)(D + o * Mq);
    const float* zc = zs[c];
    float a0 = 0.f, a1 = 0.f, a2 = 0.f, a3 = 0.f;
    #pragma unroll 8
    for (int i = 0; i < 64; ++i) {
        float4 dv = Dr[i];
        a0 = fmaf(dv.x, zc[4 * i + 0], a0);
        a1 = fmaf(dv.y, zc[4 * i + 1], a1);
        a2 = fmaf(dv.z, zc[4 * i + 2], a2);
        a3 = fmaf(dv.w, zc[4 * i + 3], a3);
    }
    ws[WS_ZC + (b4 + c) * Nq + o] =
        (a0 + a1) + (a2 + a3) + sigma[o] * noise[o * Bq + b4 + c];
}

// One distance row S from ring slot K (neighbor = slot (K+1)%6). Branchless online softmax.
#define ROWB(K, S, REFILL)                                               \
    {                                                                    \
        float4 e0 = b0[(K)], e1 = b1[(K)];                               \
        float4 n0 = b0[((K)+1)%6], n1 = b1[((K)+1)%6];                   \
        if (REFILL) {                                                    \
            const float4* rp = p4 + (size_t)min((S) + 6, 1023) * 16384;  \
            b0[(K)] = rp[0]; b1[(K)] = rp[16];                           \
        }                                                                \
        float d = ((fabsf(e0.x-zc0.x)+fabsf(e0.y-zc0.y)) +               \
                   (fabsf(e0.z-zc0.z)+fabsf(e0.w-zc0.w))) +              \
                  ((fabsf(e1.x-zc1.x)+fabsf(e1.y-zc1.y)) +               \
                   (fabsf(e1.z-zc1.z)+fabsf(e1.w-zc1.w)));               \
        d = red16(d);                                                    \
        float v = d * negt;                                              \
        float mnew = fmaxf(mrun, v);                                     \
        float sc = exp2f(mrun - mnew);                                   \
        float w  = exp2f(v - mnew);                                      \
        mrun = mnew;                                                     \
        Zrun = fmaf(Zrun, sc, w);                                        \
        a00.x=fmaf(a00.x,sc,w*e0.x); a00.y=fmaf(a00.y,sc,w*e0.y);        \
        a00.z=fmaf(a00.z,sc,w*e0.z); a00.w=fmaf(a00.w,sc,w*e0.w);        \
        a01.x=fmaf(a01.x,sc,w*e1.x); a01.y=fmaf(a01.y,sc,w*e1.y);        \
        a01.z=fmaf(a01.z,sc,w*e1.z); a01.w=fmaf(a01.w,sc,w*e1.w);        \
        a10.x=fmaf(a10.x,sc,w*n0.x); a10.y=fmaf(a10.y,sc,w*n0.y);        \
        a10.z=fmaf(a10.z,sc,w*n0.z); a10.w=fmaf(a10.w,sc,w*n0.w);        \
        a11.x=fmaf(a11.x,sc,w*n1.x); a11.y=fmaf(a11.y,sc,w*n1.y);        \
        a11.z=fmaf(a11.z,sc,w*n1.z); a11.w=fmaf(a11.w,sc,w*n1.w);        \
    }

// ---- kernel1: 256 blocks = 16 col-groups x 16 row-bands. Block reads 16KB
// CONTIGUOUS per context row (32 adjacent columns); wave = 4 columns, 16-lane
// group per column; 6-deep float4-pair ring; no LDS, no syncthreads.
extern "C" __global__ void __launch_bounds__(512)
stream_kernel(const float* __restrict__ context,
              const float* __restrict__ temp1,
              float* __restrict__ ws)
{
    const int tid  = threadIdx.x;
    const int wave = tid >> 6;
    const int lane = tid & 63;
    const int j    = lane & 15;
    const int g    = blockIdx.x & 15;          // col-group (fast dim)
    const int r    = blockIdx.x >> 4;          // band
    const int col  = g * 32 + wave * 4 + (lane >> 4);

    const int L = r * 64;
    const int H = min(1023, L + 64);           // distance rows [L,H)

    // lane's 32B of the row: float4 at col*128 + j*4 and +64 floats.
    const float4* p4 = (const float4*)context + (size_t)col * 32 + j;

    const float4 zc0 = *(const float4*)(ws + WS_ZC + (size_t)col * Nq + j * 4);
    const float4 zc1 = *(const float4*)(ws + WS_ZC + (size_t)col * Nq + 64 + j * 4);

    float4 b0[6], b1[6];
    #pragma unroll
    for (int k = 0; k < 6; ++k) {
        const float4* rp = p4 + (size_t)(L + k) * 16384;
        b0[k] = rp[0];
        b1[k] = rp[16];
    }

    const float negt = -LOG2E / fabsf(temp1[0]);
    float mrun = -INFINITY, Zrun = 0.f;
    float4 a00 = make_float4(0,0,0,0), a01 = make_float4(0,0,0,0);
    float4 a10 = make_float4(0,0,0,0), a11 = make_float4(0,0,0,0);

    int rb = L;
    for (; rb + 6 < H; rb += 6) {
        ROWB(0, rb+0, 1) ROWB(1, rb+1, 1) ROWB(2, rb+2, 1)
        ROWB(3, rb+3, 1) ROWB(4, rb+4, 1) ROWB(5, rb+5, 1)
    }
    // tail: <=4 rows (band sizes 64/63 with step 6 guarantee j<=3); neighbors resident.
    if (rb + 0 < H) ROWB(0, rb+0, 0)
    if (rb + 1 < H) ROWB(1, rb+1, 0)
    if (rb + 2 < H) ROWB(2, rb+2, 0)
    if (rb + 3 < H) ROWB(3, rb+3, 0)

    const size_t prow = (size_t)r * Bq + col;
    *(float4*)(ws + WS_A0 + prow * Nq + j * 4)      = a00;
    *(float4*)(ws + WS_A0 + prow * Nq + 64 + j * 4) = a01;
    *(float4*)(ws + WS_A1 + prow * Nq + j * 4)      = a10;
    *(float4*)(ws + WS_A1 + prow * Nq + 64 + j * 4) = a11;
    if (j == 0) {
        ws[WS_MZ + prow * 2]     = mrun;
        ws[WS_MZ + prow * 2 + 1] = Zrun;
    }
}

// ---- kernel2: merge 16 band-partials + conv contraction + MLP + softmax.
// 128 blocks x 512 threads; 4 columns per block (128-thread group each).
extern "C" __global__ void __launch_bounds__(512)
merge_kernel(const float* __restrict__ ws,
             const float* __restrict__ z,
             const float* __restrict__ conv_w,
             const float* __restrict__ conv_b,
             const float* __restrict__ W1,
             const float* __restrict__ b1,
             const float* __restrict__ W2,
             const float* __restrict__ b2,
             const float* __restrict__ temp2,
             float* __restrict__ out)
{
    const int t   = threadIdx.x;
    const int cs  = t >> 7;            // col-sub 0..3
    const int o   = t & 127;
    const int col = blockIdx.x * 4 + cs;

    __shared__ float sscl[4][16];
    __shared__ float sGz[4];
    __shared__ __align__(16) float gA0[4][128];
    __shared__ __align__(16) float gA1[4][128];
    __shared__ __align__(16) float semb[4][128];
    __shared__ __align__(16) float szcol[4][256];
    __shared__ __align__(16) float shb[4][64];

    szcol[cs][o]       = z[o * Bq + col];
    szcol[cs][o + 128] = z[(o + 128) * Bq + col];

    // per-column merge factors: lanes 0..15 of each group's first wave
    if (o < 16) {
        float m  = ws[WS_MZ + ((size_t)o * Bq + col) * 2];
        float Zp = ws[WS_MZ + ((size_t)o * Bq + col) * 2 + 1];
        float gm = red16max(m);
        float sc = exp2f(m - gm);
        float gz = red16(sc * Zp);
        sscl[cs][o] = sc;
        if (o == 0) sGz[cs] = gz;
    }
    __syncthreads();

    {
        float acc0 = 0.f, acc1 = 0.f;
        #pragma unroll
        for (int p = 0; p < NB; ++p) {
            float sc = sscl[cs][p];
            acc0 = fmaf(sc, ws[WS_A0 + ((size_t)p * Bq + col) * Nq + o], acc0);
            acc1 = fmaf(sc, ws[WS_A1 + ((size_t)p * Bq + col) * Nq + o], acc1);
        }
        gA0[cs][o] = acc0;
        gA1[cs][o] = acc1;
    }
    __syncthreads();

    // embedding[o] = (w0[o,:]·A0 + w1[o,:]·A1)/Z + conv_b[o]
    {
        const float4* wr = (const float4*)(conv_w + o * 256);
        float acc = 0.f;
        #pragma unroll 8
        for (int i = 0; i < 64; ++i) {
            float4 w4 = wr[i];   // w0[o,2i], w1[o,2i], w0[o,2i+1], w1[o,2i+1]
            acc = fmaf(w4.x, gA0[cs][2 * i], acc);
            acc = fmaf(w4.y, gA1[cs][2 * i], acc);
            acc = fmaf(w4.z, gA0[cs][2 * i + 1], acc);
            acc = fmaf(w4.w, gA1[cs][2 * i + 1], acc);
        }
        semb[cs][o] = acc / sGz[cs] + conv_b[o];
    }
    __syncthreads();

    if (o < 64) {
        const float4* w1r = (const float4*)(W1 + o * (Nq + Mq));
        float acc = b1[o];
        #pragma unroll 8
        for (int i = 0; i < 32; ++i) {
            float4 wv = w1r[i];
            acc = fmaf(wv.x, semb[cs][4 * i + 0], acc);
            acc = fmaf(wv.y, semb[cs][4 * i + 1], acc);
            acc = fmaf(wv.z, semb[cs][4 * i + 2], acc);
            acc = fmaf(wv.w, semb[cs][4 * i + 3], acc);
        }
        #pragma unroll 8
        for (int i = 0; i < 64; ++i) {
            float4 wv = w1r[32 + i];
            acc = fmaf(wv.x, szcol[cs][4 * i + 0], acc);
            acc = fmaf(wv.y, szcol[cs][4 * i + 1], acc);
            acc = fmaf(wv.z, szcol[cs][4 * i + 2], acc);
            acc = fmaf(wv.w, szcol[cs][4 * i + 3], acc);
        }
        shb[cs][o] = fmaxf(acc, 0.f);
    }
    __syncthreads();

    if (o < 64) {
        const float* w2r = W2 + o * Eq;
        float acc = b2[o];
        #pragma unroll 8
        for (int jj = 0; jj < 64; ++jj) acc = fmaf(w2r[jj], shb[cs][jj], acc);
        float v = -acc * (LOG2E / fabsf(temp2[0]));
        float mx = v;
        #pragma unroll
        for (int off = 32; off > 0; off >>= 1) mx = fmaxf(mx, __shfl_xor(mx, off, 64));
        float w = exp2f(v - mx);
        float s = w;
        #pragma unroll
        for (int off = 32; off > 0; off >>= 1) s += __shfl_xor(s, off, 64);
        out[o * Bq + col] = w / s;
    }
}

extern "C" void kernel_launch(void* const* d_in, const int* in_sizes, int n_in,
                              void* d_out, int out_size, void* d_ws, size_t ws_size,
                              hipStream_t stream) {
    const float* context = (const float*)d_in[0];
    const float* z       = (const float*)d_in[1];
    const float* noise   = (const float*)d_in[2];
    const float* conv_w  = (const float*)d_in[3];
    const float* conv_b  = (const float*)d_in[4];
    const float* D       = (const float*)d_in[5];
    const float* sigma   = (const float*)d_in[6];
    const float* temp1   = (const float*)d_in[7];
    const float* W1      = (const float*)d_in[8];
    const float* b1      = (const float*)d_in[9];
    const float* W2      = (const float*)d_in[10];
    const float* b2      = (const float*)d_in[11];
    const float* temp2   = (const float*)d_in[12];
    float* out = (float*)d_out;
    float* ws  = (float*)d_ws;

    zc_kernel<<<dim3(128), dim3(512), 0, stream>>>(z, noise, D, sigma, ws);
    stream_kernel<<<dim3(256), dim3(512), 0, stream>>>(context, temp1, ws);
    merge_kernel<<<dim3(128), dim3(512), 0, stream>>>(ws, z, conv_w, conv_b,
                                                      W1, b1, W2, b2, temp2, out);
}